// Round 7
// baseline (1451.525 us; speedup 1.0000x reference)
//
#include <hip/hip_runtime.h>
#include <hip/hip_bf16.h>

#define BB 8192
#define TT 5
#define FF 923
#define HH 64
#define NG 256    // 4*H
#define KP 1920   // padded gates K: [xc 0..922][pad][m 924..1846][pad][h 1848..1911][pad]
#define OFF_M 924
#define OFF_H 1848
#define ELD 928   // encout row stride (bf16, 16B aligned)
#define PKP 960   // proj padded K
#define GKP 960   // gamma padded K

#define OUT_IMP ((size_t)1)
#define OUT_DEC ((size_t)1 + (size_t)BB*TT*FF)

// ---- workspace layout (bytes) ----
#define H_OFF      ((size_t)256)
#define C_OFF      (H_OFF + (size_t)2097152)
#define YH_OFF     (C_OFF + (size_t)2097152)
#define UNION_OFF  (YH_OFF + (size_t)65536)
// encoder-phase view of union:
#define GATES_OFF  UNION_OFF
#define G_OFF      (UNION_OFF + (size_t)8388608)
#define ABF_OFF    (G_OFF + (size_t)10485760)
#define TDWB_OFF   (UNION_OFF + (size_t)50331648)   // after Abf
#define W1B_OFF    (TDWB_OFF + (size_t)122880)
#define W2B_OFF    (W1B_OFF + (size_t)122880)
// decoder-phase view of union (written by k_proj AFTER encoder done):
#define ENCW_OFF   UNION_OFF                         // u16, 40960*256*2 = 20971520
#define ENCA_OFF   (UNION_OFF + (size_t)20971520)    // u16, 40960*64*2  = 5242880
#define RWB_OFF    (UNION_OFF + (size_t)52428800)
#define PWB_OFF    (RWB_OFF + (size_t)983040)
#define ENCOUT_OFF (PWB_OFF + (size_t)614400)
#define ZERO_BYTES ((size_t)4194560)   // acc + h + c

typedef unsigned short u16;
typedef __bf16 bf16_8 __attribute__((ext_vector_type(8)));
typedef float  f32_4  __attribute__((ext_vector_type(4)));
typedef u16    u16_8  __attribute__((ext_vector_type(8)));
typedef float  f4u    __attribute__((ext_vector_type(4), aligned(4)));

__device__ __forceinline__ float sigm(float x){ return 1.0f/(1.0f+expf(-x)); }
__device__ __forceinline__ float rnd6(float x){ return rintf(x*1.0e6f)/1.0e6f; }
__device__ __forceinline__ u16 bf16u(float x){
  __hip_bfloat16 b = __float2bfloat16(x);
  return __builtin_bit_cast(u16, b);
}
__device__ __forceinline__ float ubf(u16 v){
  __hip_bfloat16 b = __builtin_bit_cast(__hip_bfloat16, v);
  return __bfloat162float(b);
}

__device__ __forceinline__ void acc2_block(float s1, float s2, double* a1, double* a2){
  #pragma unroll
  for (int off = 32; off > 0; off >>= 1){
    s1 += __shfl_xor(s1, off, 64);
    s2 += __shfl_xor(s2, off, 64);
  }
  __shared__ float r1[4], r2[4];
  int tid = threadIdx.x;
  if ((tid & 63) == 0){ r1[tid>>6] = s1; r2[tid>>6] = s2; }
  __syncthreads();
  if (tid == 0){
    atomicAdd(a1, (double)r1[0]+(double)r1[1]+(double)r1[2]+(double)r1[3]);
    atomicAdd(a2, (double)r2[0]+(double)r2[1]+(double)r2[2]+(double)r2[3]);
  }
}

// ---------------- P0: weight bf16 conversions + A_bf16 h-region zero ----------------
__global__ __launch_bounds__(256) void k_prep(
    const float* __restrict__ rnnWih, const float* __restrict__ rnnWhh,
    const float* __restrict__ decWih, const float* __restrict__ attW,
    const float* __restrict__ tdW, const float* __restrict__ histW,
    const float* __restrict__ encWt,
    u16* __restrict__ rnnWb, u16* __restrict__ projWb, u16* __restrict__ Abf,
    u16* __restrict__ tdWb, u16* __restrict__ W1b, u16* __restrict__ W2b)
{
  const int E1 = 256*1920, E2 = 320*960, E3 = 8192*64, E4 = 64*960, E5 = 960*64;
  int idx = blockIdx.x*256 + threadIdx.x;
  if (idx < E1) {
    int n = idx / 1920, k = idx % 1920;
    float v = 0.0f;
    if (k < 923)                    v = rnnWih[(size_t)n*1846 + k];
    else if (k >= 924 && k < 1847)  v = rnnWih[(size_t)n*1846 + (k-1)];
    else if (k >= 1848 && k < 1912) v = rnnWhh[(size_t)n*64 + (k-1848)];
    rnnWb[idx] = bf16u(v);
  } else if ((idx -= E1) < E2) {
    int n = idx / 960, k = idx % 960;
    float v = 0.0f;
    if (k < 923)
      v = (n < NG) ? decWih[(size_t)n*(FF+2) + 2 + k]
                   : attW[(size_t)(n-NG)*(FF+HH) + HH + k];
    projWb[idx] = bf16u(v);
  } else if ((idx -= E2) < E3) {
    int b = idx >> 6, u = idx & 63;
    Abf[(size_t)b*KP + OFF_H + u] = 0;
  } else if ((idx -= E3) < E4) {
    int n = idx / 960, k = idx % 960;
    tdWb[idx] = (k < FF) ? bf16u(tdW[(size_t)n*FF + k]) : (u16)0;
  } else if ((idx -= E4) < E5) {
    int r = idx >> 6, k = idx & 63;
    W1b[idx] = (r < FF) ? bf16u(histW[(size_t)r*HH + k]) : (u16)0;
  } else {
    idx -= E5;
    int r = idx >> 6, k = idx & 63;
    W2b[idx] = (r < FF) ? bf16u(encWt[(size_t)r*HH + k]) : (u16)0;
  }
}

// ---------------- P1: G = exp(-relu(deltas @ tdW^T + tdb)) — barrier-free MFMA stream ----------------
// one wave = 16 rows, block = 4 waves, grid 640; A direct from global fp32 (converted
// in-register), B direct from L2-resident tdWb. No LDS, no barriers.
__global__ __launch_bounds__(256) void k_gamma_mfma(
    const float* __restrict__ deltas, const u16* __restrict__ tdWb,
    const float* __restrict__ tdb, float* __restrict__ G)
{
  int tid = threadIdx.x;
  int wid = tid >> 6, lane = tid & 63;
  int row0 = blockIdx.x*64 + wid*16;
  int l15 = lane & 15, lk8 = (lane >> 4)*8;
  const float* Dg = deltas + (size_t)(row0 + l15)*FF;
  f32_4 acc[4] = {};
  #pragma unroll 2
  for (int k0 = 0; k0 < 928; k0 += 32) {
    int kb = k0 + lk8;
    u16_8 au;
    if (kb <= 915) {
      f4u v0 = *(const f4u*)(Dg + kb);
      f4u v1 = *(const f4u*)(Dg + kb + 4);
      #pragma unroll
      for (int j = 0; j < 4; ++j) { au[j] = bf16u(v0[j]); au[4+j] = bf16u(v1[j]); }
    } else {
      #pragma unroll
      for (int j = 0; j < 8; ++j) au[j] = (kb + j < FF) ? bf16u(Dg[kb+j]) : (u16)0;
    }
    bf16_8 av = __builtin_bit_cast(bf16_8, au);
    #pragma unroll
    for (int ni = 0; ni < 4; ++ni) {
      bf16_8 bv = *(const bf16_8*)(tdWb + (size_t)(ni*16 + l15)*GKP + kb);
      acc[ni] = __builtin_amdgcn_mfma_f32_16x16x32_bf16(av, bv, acc[ni], 0, 0, 0);
    }
  }
  #pragma unroll
  for (int ni = 0; ni < 4; ++ni) {
    int col = ni*16 + l15;
    float bb = tdb[col];
    #pragma unroll
    for (int r = 0; r < 4; ++r) {
      int row = row0 + (lane>>4)*4 + r;
      G[(size_t)row*HH + col] = expf(-fmaxf(acc[ni][r] + bb, 0.0f));
    }
  }
}

// ---------------- K2: x_h & enc via MFMA (K=64), fused epilogue ----------------
__global__ __launch_bounds__(256) void k_xh_enc_mfma(
    const float* __restrict__ values, const float* __restrict__ masks,
    const u16* __restrict__ W1b, const u16* __restrict__ W2b,
    const float* __restrict__ histb, const float* __restrict__ encb,
    float* __restrict__ out, u16* __restrict__ Abf, u16* __restrict__ encout,
    double* __restrict__ acc, int t)
{
  __shared__ __align__(16) u16 As[64*64];
  __shared__ __align__(16) u16 B1s[64*64];
  __shared__ __align__(16) u16 B2s[64*64];
  int tid = threadIdx.x;
  int m0 = blockIdx.x*64, c0 = blockIdx.y*64;
  int srow = tid >> 2, sseg = tid & 3;
  int wid = tid >> 6, lane = tid & 63;
  int wr = (wid >> 1)*32, wc = (wid & 1)*32;
  int l15 = lane & 15, lk8 = (lane >> 4)*8;
  f32_4 a1c[2][2] = {}, a2c[2][2] = {};
  char* AsB = (char*)As;
  char* B1B = (char*)B1s;
  char* B2B = (char*)B2s;
  int wb = srow*128 + sseg*32;
  int swz = (srow & 7) << 4;
  {
    const u16* Ag = Abf + (size_t)(m0+srow)*KP + OFF_H + sseg*16;
    const u16* W1g = W1b + (size_t)(c0+srow)*HH + sseg*16;
    const u16* W2g = W2b + (size_t)(c0+srow)*HH + sseg*16;
    u16_8 a0 = *(const u16_8*)(Ag);
    u16_8 a1 = *(const u16_8*)(Ag + 8);
    u16_8 w10 = *(const u16_8*)(W1g);
    u16_8 w11 = *(const u16_8*)(W1g + 8);
    u16_8 w20 = *(const u16_8*)(W2g);
    u16_8 w21 = *(const u16_8*)(W2g + 8);
    *(u16_8*)(AsB + ((wb     ) ^ swz)) = a0;
    *(u16_8*)(AsB + ((wb + 16) ^ swz)) = a1;
    *(u16_8*)(B1B + ((wb     ) ^ swz)) = w10;
    *(u16_8*)(B1B + ((wb + 16) ^ swz)) = w11;
    *(u16_8*)(B2B + ((wb     ) ^ swz)) = w20;
    *(u16_8*)(B2B + ((wb + 16) ^ swz)) = w21;
  }
  __syncthreads();
  #pragma unroll
  for (int kk = 0; kk < 64; kk += 32) {
    bf16_8 av[2], b1v[2], b2v[2];
    #pragma unroll
    for (int mi = 0; mi < 2; ++mi) {
      int r = wr + mi*16 + l15;
      av[mi] = *(const bf16_8*)(AsB + ((r*128 + (kk+lk8)*2) ^ ((r&7)<<4)));
    }
    #pragma unroll
    for (int ni = 0; ni < 2; ++ni) {
      int cc = wc + ni*16 + l15;
      b1v[ni] = *(const bf16_8*)(B1B + ((cc*128 + (kk+lk8)*2) ^ ((cc&7)<<4)));
      b2v[ni] = *(const bf16_8*)(B2B + ((cc*128 + (kk+lk8)*2) ^ ((cc&7)<<4)));
    }
    #pragma unroll
    for (int mi = 0; mi < 2; ++mi)
      #pragma unroll
      for (int ni = 0; ni < 2; ++ni) {
        a1c[mi][ni] = __builtin_amdgcn_mfma_f32_16x16x32_bf16(av[mi], b1v[ni], a1c[mi][ni], 0, 0, 0);
        a2c[mi][ni] = __builtin_amdgcn_mfma_f32_16x16x32_bf16(av[mi], b2v[ni], a2c[mi][ni], 0, 0, 0);
      }
  }
  float s1 = 0.0f, sm = 0.0f;
  #pragma unroll
  for (int mi = 0; mi < 2; ++mi)
    #pragma unroll
    for (int ni = 0; ni < 2; ++ni) {
      int col = c0 + wc + ni*16 + l15;
      if (col < FF) {
        float hb = histb[col], eb = encb[col];
        #pragma unroll
        for (int r = 0; r < 4; ++r) {
          int row = m0 + wr + mi*16 + (lane>>4)*4 + r;
          size_t off = ((size_t)row*TT + t)*FF + col;
          float xh = a1c[mi][ni][r] + hb;
          float x = values[off], m = masks[off];
          float xc = m*x + (1.0f - m)*xh;
          out[OUT_IMP + off] = rnd6(xc);
          Abf[(size_t)row*KP + col] = bf16u(xc);
          Abf[(size_t)row*KP + OFF_M + col] = bf16u(m);
          float e = tanhf(a2c[mi][ni][r] + eb) * m;
          encout[((size_t)row*TT + t)*ELD + col] = bf16u(e);
          float d = x - xh;
          s1 += m*d*d;
          sm += m;
        }
      }
    }
  acc2_block(s1, sm, &acc[t], &acc[5+t]);
}

// ---------------- K3a: gates MFMA GEMM: [8192 x 1920] bf16 @ [256 x 1920]^T ----------------
__global__ __launch_bounds__(256) void k_gates_mfma(
    const u16* __restrict__ A, const u16* __restrict__ W,
    const float* __restrict__ bias, float* __restrict__ gates)
{
  __shared__ __align__(16) u16 As[64*64];
  __shared__ __align__(16) u16 Bs[64*64];
  int tid = threadIdx.x;
  int m0 = blockIdx.x*64, n0 = blockIdx.y*64;
  int srow = tid >> 2, sseg = tid & 3;
  int wid = tid >> 6, lane = tid & 63;
  int wr = (wid >> 1)*32, wc = (wid & 1)*32;
  int l15 = lane & 15, lk8 = (lane >> 4)*8;
  f32_4 acc[2][2] = {};
  const u16* Ag = A + (size_t)(m0+srow)*KP + sseg*16;
  const u16* Wg = W + (size_t)(n0+srow)*KP + sseg*16;
  char* AsB = (char*)As;
  char* BsB = (char*)Bs;
  int wb = srow*128 + sseg*32;
  int swz = (srow & 7) << 4;
  for (int k0 = 0; k0 < KP; k0 += 64) {
    u16_8 a0 = *(const u16_8*)(Ag + k0);
    u16_8 a1 = *(const u16_8*)(Ag + k0 + 8);
    u16_8 b0 = *(const u16_8*)(Wg + k0);
    u16_8 b1 = *(const u16_8*)(Wg + k0 + 8);
    *(u16_8*)(AsB + ((wb     ) ^ swz)) = a0;
    *(u16_8*)(AsB + ((wb + 16) ^ swz)) = a1;
    *(u16_8*)(BsB + ((wb     ) ^ swz)) = b0;
    *(u16_8*)(BsB + ((wb + 16) ^ swz)) = b1;
    __syncthreads();
    #pragma unroll
    for (int kk = 0; kk < 64; kk += 32) {
      bf16_8 av[2], bv[2];
      #pragma unroll
      for (int mi = 0; mi < 2; ++mi) {
        int r = wr + mi*16 + l15;
        av[mi] = *(const bf16_8*)(AsB + ((r*128 + (kk+lk8)*2) ^ ((r&7)<<4)));
      }
      #pragma unroll
      for (int ni = 0; ni < 2; ++ni) {
        int cc = wc + ni*16 + l15;
        bv[ni] = *(const bf16_8*)(BsB + ((cc*128 + (kk+lk8)*2) ^ ((cc&7)<<4)));
      }
      #pragma unroll
      for (int mi = 0; mi < 2; ++mi)
        #pragma unroll
        for (int ni = 0; ni < 2; ++ni)
          acc[mi][ni] = __builtin_amdgcn_mfma_f32_16x16x32_bf16(av[mi], bv[ni], acc[mi][ni], 0, 0, 0);
    }
    __syncthreads();
  }
  #pragma unroll
  for (int mi = 0; mi < 2; ++mi)
    #pragma unroll
    for (int ni = 0; ni < 2; ++ni) {
      int col = n0 + wc + ni*16 + l15;
      float bb = bias[col];
      #pragma unroll
      for (int r = 0; r < 4; ++r) {
        int row = m0 + wr + mi*16 + (lane>>4)*4 + r;
        gates[(size_t)row*NG + col] = acc[mi][ni][r] + bb;
      }
    }
}

// ---------------- K4: proj MFMA GEMM -> bf16 outputs ----------------
__global__ __launch_bounds__(256) void k_proj_mfma(
    const u16* __restrict__ A, const u16* __restrict__ W,
    const float* __restrict__ attb,
    u16* __restrict__ encWpB, u16* __restrict__ encAB)
{
  __shared__ __align__(16) u16 As[64*64];
  __shared__ __align__(16) u16 Bs[64*64];
  int tid = threadIdx.x;
  int m0 = blockIdx.x*64, n0 = blockIdx.y*64;
  int srow = tid >> 2, sseg = tid & 3;
  int wid = tid >> 6, lane = tid & 63;
  int wr = (wid >> 1)*32, wc = (wid & 1)*32;
  int l15 = lane & 15, lk8 = (lane >> 4)*8;
  f32_4 acc[2][2] = {};
  const u16* Ag = A + (size_t)(m0+srow)*ELD + sseg*16;
  const u16* Wg = W + (size_t)(n0+srow)*PKP + sseg*16;
  char* AsB = (char*)As;
  char* BsB = (char*)Bs;
  int wb = srow*128 + sseg*32;
  int swz = (srow & 7) << 4;
  for (int k0 = 0; k0 < PKP; k0 += 64) {
    u16_8 a0, a1;
    if (k0 < ELD) {
      a0 = *(const u16_8*)(Ag + k0);
      a1 = *(const u16_8*)(Ag + k0 + 8);
    } else {
      a0 = (u16_8)0; a1 = (u16_8)0;
    }
    u16_8 b0 = *(const u16_8*)(Wg + k0);
    u16_8 b1 = *(const u16_8*)(Wg + k0 + 8);
    *(u16_8*)(AsB + ((wb     ) ^ swz)) = a0;
    *(u16_8*)(AsB + ((wb + 16) ^ swz)) = a1;
    *(u16_8*)(BsB + ((wb     ) ^ swz)) = b0;
    *(u16_8*)(BsB + ((wb + 16) ^ swz)) = b1;
    __syncthreads();
    #pragma unroll
    for (int kk = 0; kk < 64; kk += 32) {
      bf16_8 av[2], bv[2];
      #pragma unroll
      for (int mi = 0; mi < 2; ++mi) {
        int r = wr + mi*16 + l15;
        av[mi] = *(const bf16_8*)(AsB + ((r*128 + (kk+lk8)*2) ^ ((r&7)<<4)));
      }
      #pragma unroll
      for (int ni = 0; ni < 2; ++ni) {
        int cc = wc + ni*16 + l15;
        bv[ni] = *(const bf16_8*)(BsB + ((cc*128 + (kk+lk8)*2) ^ ((cc&7)<<4)));
      }
      #pragma unroll
      for (int mi = 0; mi < 2; ++mi)
        #pragma unroll
        for (int ni = 0; ni < 2; ++ni)
          acc[mi][ni] = __builtin_amdgcn_mfma_f32_16x16x32_bf16(av[mi], bv[ni], acc[mi][ni], 0, 0, 0);
    }
    __syncthreads();
  }
  #pragma unroll
  for (int mi = 0; mi < 2; ++mi)
    #pragma unroll
    for (int ni = 0; ni < 2; ++ni) {
      int col = n0 + wc + ni*16 + l15;
      if (col < NG) {
        #pragma unroll
        for (int r = 0; r < 4; ++r) {
          int row = m0 + wr + mi*16 + (lane>>4)*4 + r;
          encWpB[(size_t)row*NG + col] = bf16u(acc[mi][ni][r]);
        }
      } else {
        float bb = attb[col - NG];
        #pragma unroll
        for (int r = 0; r < 4; ++r) {
          int row = m0 + wr + mi*16 + (lane>>4)*4 + r;
          encAB[(size_t)row*HH + (col - NG)] = bf16u(acc[mi][ni][r] + bb);
        }
      }
    }
}

// ---------------- K3b: LSTM pointwise + fused next-step gamma + bf16 h ----------------
__global__ __launch_bounds__(256) void k_lstm(
    const float* __restrict__ gates, float* __restrict__ h, float* __restrict__ c,
    const float* __restrict__ G, u16* __restrict__ Abf, int t)
{
  int idx = blockIdx.x*256 + threadIdx.x;
  int b = idx >> 6, u = idx & 63;
  const float* g = gates + (size_t)b*NG;
  float gi = g[u], gf = g[64+u], gg = g[128+u], go = g[192+u];
  float cn = sigm(gf)*c[idx] + sigm(gi)*tanhf(gg);
  float hn = sigm(go)*tanhf(cn);
  c[idx] = cn;
  float hs = hn;
  if (t < TT-1) hs *= G[((size_t)b*TT + t + 1)*HH + u];
  h[idx] = hs;
  Abf[(size_t)b*KP + OFF_H + u] = bf16u(hs);
}

// ---------------- K5: y_h init, decoded[:,T-1], y_loss td=0 ----------------
__global__ __launch_bounds__(256) void k_yh0(
    const float* __restrict__ h, const float* __restrict__ outW,
    const float* __restrict__ outb, const float* __restrict__ labels,
    const float* __restrict__ masksy, float* __restrict__ out,
    float* __restrict__ yh, double* __restrict__ acc)
{
  int b = blockIdx.x*256 + threadIdx.x;
  float y0 = outb[0], y1 = outb[1];
  const float* hb = h + (size_t)b*HH;
  for (int j = 0; j < HH; ++j) {
    float hv = hb[j];
    y0 = fmaf(hv, outW[j], y0);
    y1 = fmaf(hv, outW[HH+j], y1);
  }
  size_t lo = ((size_t)b*TT + (TT-1))*2;
  float l0 = labels[lo], l1 = labels[lo+1];
  float m0 = masksy[lo], m1 = masksy[lo+1];
  float d0 = (y0-l0)*m0, d1 = (y1-l1)*m1;
  out[OUT_DEC + lo]   = rnd6(l0*m0 + y0*(1.0f-m0));
  out[OUT_DEC + lo+1] = rnd6(l1*m1 + y1*(1.0f-m1));
  yh[b*2]   = y0;
  yh[b*2+1] = y1;
  acc2_block(d0*d0 + d1*d1, m0+m1, &acc[10], &acc[15]);
}

// ---------------- K6: decoder step — minimal LDS, weights direct from L2 ----------------
__global__ __launch_bounds__(256) void k_dec(
    const float* __restrict__ labels, const float* __restrict__ masksy,
    const float* __restrict__ decWih, const float* __restrict__ decWhh,
    const float* __restrict__ decb, const float* __restrict__ attW,
    const float* __restrict__ attv, const float* __restrict__ outW,
    const float* __restrict__ outb, float* __restrict__ h, float* __restrict__ c,
    float* __restrict__ yh, const u16* __restrict__ encWpB,
    const u16* __restrict__ encAB, float* __restrict__ out,
    double* __restrict__ acc, int td)
{
  __shared__ float hb4[4][64];
  int tid = threadIdx.x;
  int wid = tid >> 6, lane = tid & 63;
  int b = blockIdx.x*4 + wid;
  float hj = h[(size_t)b*HH + lane];
  float cj = c[(size_t)b*HH + lane];
  hb4[wid][lane] = hj;
  __syncthreads();

  // h_att[lane] = sum_k attW[lane,k]*h[k]  (attW row direct from L2)
  float hatt = 0.0f;
  const float* aWrow = attW + (size_t)lane*(FF+HH);
  #pragma unroll
  for (int k4 = 0; k4 < 16; ++k4) {
    f4u w = *(const f4u*)(aWrow + k4*4);
    float4 hv = *(const float4*)&hb4[wid][k4*4];
    hatt += w[0]*hv.x + w[1]*hv.y + w[2]*hv.z + w[3]*hv.w;
  }
  float sc[5];
  float vj = attv[lane];
  #pragma unroll
  for (int s = 0; s < 5; ++s) {
    float e = tanhf(hatt + ubf(encAB[((size_t)b*TT + s)*HH + lane]));
    float p = e*vj;
    #pragma unroll
    for (int off = 32; off > 0; off >>= 1) p += __shfl_xor(p, off, 64);
    sc[s] = p;
  }
  float mx = fmaxf(fmaxf(fmaxf(sc[0],sc[1]),fmaxf(sc[2],sc[3])),sc[4]);
  float se = 0.0f;
  #pragma unroll
  for (int s = 0; s < 5; ++s) { sc[s] = expf(sc[s]-mx); se += sc[s]; }
  float inv = 1.0f/se;
  #pragma unroll
  for (int s = 0; s < 5; ++s) sc[s] *= inv;
  int tt = TT-1-td;
  size_t lo = ((size_t)b*TT + tt)*2;
  float l0 = labels[lo], l1 = labels[lo+1];
  float m0 = masksy[lo], m1 = masksy[lo+1];
  float py0 = yh[b*2], py1 = yh[b*2+1];
  float iy0 = fmaf(l0, m0, py0*(1.0f-m0));
  float iy1 = fmaf(l1, m1, py1*(1.0f-m1));
  if (lane < 2) out[OUT_DEC + lo + lane] = rnd6(lane ? iy1 : iy0);
  float g[4];
  #pragma unroll
  for (int gi = 0; gi < 4; ++gi) {
    int jj = gi*64 + lane;
    float a = decb[jj] + iy0*decWih[(size_t)jj*(FF+2)] + iy1*decWih[(size_t)jj*(FF+2) + 1];
    #pragma unroll
    for (int s = 0; s < 5; ++s)
      a = fmaf(sc[s], ubf(encWpB[((size_t)b*TT + s)*NG + jj]), a);
    float aa = 0.0f;
    const float* whrow = decWhh + (size_t)jj*HH;
    #pragma unroll
    for (int k4 = 0; k4 < 16; ++k4) {
      float4 w = *(const float4*)(whrow + k4*4);
      float4 hv = *(const float4*)&hb4[wid][k4*4];
      aa += w.x*hv.x + w.y*hv.y + w.z*hv.z + w.w*hv.w;
    }
    g[gi] = a + aa;
  }
  float cn = sigm(g[1])*cj + sigm(g[0])*tanhf(g[2]);
  float hn = sigm(g[3])*tanhf(cn);
  c[(size_t)b*HH + lane] = cn;
  h[(size_t)b*HH + lane] = hn;
  float p0 = hn*outW[lane], p1 = hn*outW[HH+lane];
  #pragma unroll
  for (int off = 32; off > 0; off >>= 1) {
    p0 += __shfl_xor(p0, off, 64);
    p1 += __shfl_xor(p1, off, 64);
  }
  float ny0 = p0 + outb[0], ny1 = p1 + outb[1];
  if (lane == 0) { yh[b*2] = ny0; yh[b*2+1] = ny1; }
  float d0 = (ny0-l0)*m0, d1 = (ny1-l1)*m1;
  float sl  = (lane==0) ? (d0*d0 + d1*d1) : 0.0f;
  float smk = (lane==0) ? (m0+m1) : 0.0f;
  acc2_block(sl, smk, &acc[10+td], &acc[15+td]);
}

// ---------------- K7: finalize loss ----------------
__global__ void k_loss(const double* __restrict__ acc, float* __restrict__ out)
{
  if (threadIdx.x == 0 && blockIdx.x == 0) {
    double xl = 0.0, yl = 0.0;
    for (int t = 0; t < 5; ++t)
      xl += acc[t] / ((double)BB*FF) / (acc[5+t] + 1e-5);
    for (int d = 0; d < 5; ++d)
      yl += acc[10+d] / ((double)BB*2) / (acc[15+d] + 1e-5);
    out[0] = (float)((xl + yl) / 5.0);
  }
}

extern "C" void kernel_launch(void* const* d_in, const int* in_sizes, int n_in,
                              void* d_out, int out_size, void* d_ws, size_t ws_size,
                              hipStream_t stream)
{
  const float* values = (const float*)d_in[0];
  const float* masks  = (const float*)d_in[1];
  const float* deltas = (const float*)d_in[2];
  const float* labels = (const float*)d_in[3];
  const float* masksy = (const float*)d_in[4];
  const float* tdW    = (const float*)d_in[5];
  const float* tdb    = (const float*)d_in[6];
  const float* histW  = (const float*)d_in[7];
  const float* histb  = (const float*)d_in[8];
  const float* encWt  = (const float*)d_in[9];
  const float* encb   = (const float*)d_in[10];
  const float* rnnWih = (const float*)d_in[11];
  const float* rnnWhh = (const float*)d_in[12];
  const float* rnnb   = (const float*)d_in[13];
  const float* decWih = (const float*)d_in[14];
  const float* decWhh = (const float*)d_in[15];
  const float* decb   = (const float*)d_in[16];
  const float* attW   = (const float*)d_in[17];
  const float* attb   = (const float*)d_in[18];
  const float* attv   = (const float*)d_in[19];
  const float* outW   = (const float*)d_in[20];
  const float* outb   = (const float*)d_in[21];
  float* out = (float*)d_out;
  char* ws = (char*)d_ws;
  double* acc = (double*)ws;
  float* h      = (float*)(ws + H_OFF);
  float* c      = (float*)(ws + C_OFF);
  float* yh     = (float*)(ws + YH_OFF);
  float* gates  = (float*)(ws + GATES_OFF);
  float* G      = (float*)(ws + G_OFF);
  u16*   Abf    = (u16*)(ws + ABF_OFF);
  u16*   tdWb   = (u16*)(ws + TDWB_OFF);
  u16*   W1b    = (u16*)(ws + W1B_OFF);
  u16*   W2b    = (u16*)(ws + W2B_OFF);
  u16*   encWpB = (u16*)(ws + ENCW_OFF);
  u16*   encAB  = (u16*)(ws + ENCA_OFF);
  u16*   rnnWb  = (u16*)(ws + RWB_OFF);
  u16*   projWb = (u16*)(ws + PWB_OFF);
  u16*   encout = (u16*)(ws + ENCOUT_OFF);

  (void)hipMemsetAsync(d_ws, 0, ZERO_BYTES, stream);

  k_prep<<<5888, 256, 0, stream>>>(rnnWih, rnnWhh, decWih, attW, tdW, histW, encWt,
                                   rnnWb, projWb, Abf, tdWb, W1b, W2b);
  k_gamma_mfma<<<640, 256, 0, stream>>>(deltas, tdWb, tdb, G);

  for (int t = 0; t < TT; ++t) {
    k_xh_enc_mfma<<<dim3(BB/64, 15), 256, 0, stream>>>(values, masks, W1b, W2b,
                                                       histb, encb, out, Abf, encout, acc, t);
    k_gates_mfma<<<dim3(BB/64, 4), 256, 0, stream>>>(Abf, rnnWb, rnnb, gates);
    k_lstm<<<BB*HH/256, 256, 0, stream>>>(gates, h, c, G, Abf, t);
  }
  k_proj_mfma<<<dim3(BB*TT/64, 5), 256, 0, stream>>>(encout, projWb, attb, encWpB, encAB);
  k_yh0<<<BB/256, 256, 0, stream>>>(h, outW, outb, labels, masksy, out, yh, acc);
  for (int td = 1; td < TT; ++td) {
    k_dec<<<BB/4, 256, 0, stream>>>(labels, masksy, decWih, decWhh, decb, attW,
                                    attv, outW, outb, h, c, yh, encWpB, encAB, out, acc, td);
  }
  k_loss<<<1, 1, 0, stream>>>(acc, out);
}

// Round 8
// 1260.669 us; speedup vs baseline: 1.1514x; 1.1514x over previous
//
#include <hip/hip_runtime.h>
#include <hip/hip_bf16.h>

#define BB 8192
#define TT 5
#define FF 923
#define HH 64
#define NG 256    // 4*H
#define KP 1920   // padded gates K: [xc 0..922][pad][m 924..1846][pad][h 1848..1911][pad]
#define OFF_M 924
#define OFF_H 1848
#define ELD 928   // encout row stride (bf16, 16B aligned)
#define PKP 960   // proj padded K
#define GKP 960   // gamma padded K
#define DN  320   // decoder GEMM N: 64 att + 256 gates

#define OUT_IMP ((size_t)1)
#define OUT_DEC ((size_t)1 + (size_t)BB*TT*FF)

// ---- workspace layout (bytes) ----
#define H_OFF      ((size_t)256)
#define C_OFF      (H_OFF + (size_t)2097152)
#define YH_OFF     (C_OFF + (size_t)2097152)
#define UNION_OFF  (YH_OFF + (size_t)65536)
// encoder-phase view of union:
#define GATES_OFF  UNION_OFF
#define G_OFF      (UNION_OFF + (size_t)8388608)
#define ABF_OFF    (G_OFF + (size_t)10485760)
#define TDWB_OFF   (UNION_OFF + (size_t)50331648)   // after Abf
#define W1B_OFF    (TDWB_OFF + (size_t)122880)
#define W2B_OFF    (W1B_OFF + (size_t)122880)
// persistent mini-region in the gap (survives both phases; below RWB, above ENCA end):
#define DWCAT_OFF  (UNION_OFF + (size_t)50700288)   // 320*64*2 = 40960
#define DW01_OFF   (UNION_OFF + (size_t)50741248)   // 512*4 = 2048
#define HB16_OFF   (UNION_OFF + (size_t)50743296)   // 8192*64*2 = 1048576 (ends 51791872 < 52428800)
// decoder-phase view of union (written by k_proj AFTER encoder done):
#define ENCW_OFF   UNION_OFF                         // u16, 40960*256*2 = 20971520
#define ENCA_OFF   (UNION_OFF + (size_t)20971520)    // u16, 40960*64*2  = 5242880
#define RWB_OFF    (UNION_OFF + (size_t)52428800)
#define PWB_OFF    (RWB_OFF + (size_t)983040)
#define ENCOUT_OFF (PWB_OFF + (size_t)614400)
#define P_OFF      ENCOUT_OFF                        // f32 8192*320*4 (encout dead after k_proj)
#define ZERO_BYTES ((size_t)4194560)   // acc + h + c

typedef unsigned short u16;
typedef __bf16 bf16_8 __attribute__((ext_vector_type(8)));
typedef float  f32_4  __attribute__((ext_vector_type(4)));
typedef u16    u16_8  __attribute__((ext_vector_type(8)));
typedef float  f4u    __attribute__((ext_vector_type(4), aligned(4)));

__device__ __forceinline__ float sigm(float x){ return 1.0f/(1.0f+expf(-x)); }
__device__ __forceinline__ float rnd6(float x){ return rintf(x*1.0e6f)/1.0e6f; }
__device__ __forceinline__ u16 bf16u(float x){
  __hip_bfloat16 b = __float2bfloat16(x);
  return __builtin_bit_cast(u16, b);
}
__device__ __forceinline__ float ubf(u16 v){
  __hip_bfloat16 b = __builtin_bit_cast(__hip_bfloat16, v);
  return __bfloat162float(b);
}

__device__ __forceinline__ void acc2_block(float s1, float s2, double* a1, double* a2){
  #pragma unroll
  for (int off = 32; off > 0; off >>= 1){
    s1 += __shfl_xor(s1, off, 64);
    s2 += __shfl_xor(s2, off, 64);
  }
  __shared__ float r1[4], r2[4];
  int tid = threadIdx.x;
  if ((tid & 63) == 0){ r1[tid>>6] = s1; r2[tid>>6] = s2; }
  __syncthreads();
  if (tid == 0){
    atomicAdd(a1, (double)r1[0]+(double)r1[1]+(double)r1[2]+(double)r1[3]);
    atomicAdd(a2, (double)r2[0]+(double)r2[1]+(double)r2[2]+(double)r2[3]);
  }
}

// ---------------- P0: weight bf16 conversions + A_bf16 h-region zero ----------------
__global__ __launch_bounds__(256) void k_prep(
    const float* __restrict__ rnnWih, const float* __restrict__ rnnWhh,
    const float* __restrict__ decWih, const float* __restrict__ attW,
    const float* __restrict__ tdW, const float* __restrict__ histW,
    const float* __restrict__ encWt, const float* __restrict__ decWhh,
    u16* __restrict__ rnnWb, u16* __restrict__ projWb, u16* __restrict__ Abf,
    u16* __restrict__ tdWb, u16* __restrict__ W1b, u16* __restrict__ W2b,
    u16* __restrict__ dwcat, float* __restrict__ dw01)
{
  const int E1 = 256*1920, E2 = 320*960, E3 = 8192*64, E4 = 64*960, EW = 960*64;
  const int E6 = 320*64, E7 = 512;
  int idx = blockIdx.x*256 + threadIdx.x;
  if (idx < E1) {
    int n = idx / 1920, k = idx % 1920;
    float v = 0.0f;
    if (k < 923)                    v = rnnWih[(size_t)n*1846 + k];
    else if (k >= 924 && k < 1847)  v = rnnWih[(size_t)n*1846 + (k-1)];
    else if (k >= 1848 && k < 1912) v = rnnWhh[(size_t)n*64 + (k-1848)];
    rnnWb[idx] = bf16u(v);
  } else if ((idx -= E1) < E2) {
    int n = idx / 960, k = idx % 960;
    float v = 0.0f;
    if (k < 923)
      v = (n < NG) ? decWih[(size_t)n*(FF+2) + 2 + k]
                   : attW[(size_t)(n-NG)*(FF+HH) + HH + k];
    projWb[idx] = bf16u(v);
  } else if ((idx -= E2) < E3) {
    int b = idx >> 6, u = idx & 63;
    Abf[(size_t)b*KP + OFF_H + u] = 0;
  } else if ((idx -= E3) < E4) {
    int n = idx / 960, k = idx % 960;
    tdWb[idx] = (k < FF) ? bf16u(tdW[(size_t)n*FF + k]) : (u16)0;
  } else if ((idx -= E4) < EW) {
    int r = idx >> 6, k = idx & 63;
    W1b[idx] = (r < FF) ? bf16u(histW[(size_t)r*HH + k]) : (u16)0;
  } else if ((idx -= EW) < EW) {
    int r = idx >> 6, k = idx & 63;
    W2b[idx] = (r < FF) ? bf16u(encWt[(size_t)r*HH + k]) : (u16)0;
  } else if ((idx -= EW) < E6) {
    int n = idx >> 6, k = idx & 63;
    float v = (n < HH) ? attW[(size_t)n*(FF+HH) + k]
                       : decWhh[(size_t)(n-HH)*HH + k];
    dwcat[idx] = bf16u(v);
  } else if ((idx -= E6) < E7) {
    int jj = idx >> 1, col = idx & 1;
    dw01[idx] = decWih[(size_t)jj*(FF+2) + col];
  }
}

// ---------------- P1: G = exp(-relu(deltas @ tdW^T + tdb)) — barrier-free MFMA stream ----------------
__global__ __launch_bounds__(256) void k_gamma_mfma(
    const float* __restrict__ deltas, const u16* __restrict__ tdWb,
    const float* __restrict__ tdb, float* __restrict__ G)
{
  int tid = threadIdx.x;
  int wid = tid >> 6, lane = tid & 63;
  int row0 = blockIdx.x*64 + wid*16;
  int l15 = lane & 15, lk8 = (lane >> 4)*8;
  const float* Dg = deltas + (size_t)(row0 + l15)*FF;
  f32_4 acc[4] = {};
  #pragma unroll 2
  for (int k0 = 0; k0 < 928; k0 += 32) {
    int kb = k0 + lk8;
    u16_8 au;
    if (kb <= 915) {
      f4u v0 = *(const f4u*)(Dg + kb);
      f4u v1 = *(const f4u*)(Dg + kb + 4);
      #pragma unroll
      for (int j = 0; j < 4; ++j) { au[j] = bf16u(v0[j]); au[4+j] = bf16u(v1[j]); }
    } else {
      #pragma unroll
      for (int j = 0; j < 8; ++j) au[j] = (kb + j < FF) ? bf16u(Dg[kb+j]) : (u16)0;
    }
    bf16_8 av = __builtin_bit_cast(bf16_8, au);
    #pragma unroll
    for (int ni = 0; ni < 4; ++ni) {
      bf16_8 bv = *(const bf16_8*)(tdWb + (size_t)(ni*16 + l15)*GKP + kb);
      acc[ni] = __builtin_amdgcn_mfma_f32_16x16x32_bf16(av, bv, acc[ni], 0, 0, 0);
    }
  }
  #pragma unroll
  for (int ni = 0; ni < 4; ++ni) {
    int col = ni*16 + l15;
    float bb = tdb[col];
    #pragma unroll
    for (int r = 0; r < 4; ++r) {
      int row = row0 + (lane>>4)*4 + r;
      G[(size_t)row*HH + col] = expf(-fmaxf(acc[ni][r] + bb, 0.0f));
    }
  }
}

// ---------------- K2: x_h & enc via MFMA (K=64), fused epilogue ----------------
__global__ __launch_bounds__(256) void k_xh_enc_mfma(
    const float* __restrict__ values, const float* __restrict__ masks,
    const u16* __restrict__ W1b, const u16* __restrict__ W2b,
    const float* __restrict__ histb, const float* __restrict__ encb,
    float* __restrict__ out, u16* __restrict__ Abf, u16* __restrict__ encout,
    double* __restrict__ acc, int t)
{
  __shared__ __align__(16) u16 As[64*64];
  __shared__ __align__(16) u16 B1s[64*64];
  __shared__ __align__(16) u16 B2s[64*64];
  int tid = threadIdx.x;
  int m0 = blockIdx.x*64, c0 = blockIdx.y*64;
  int srow = tid >> 2, sseg = tid & 3;
  int wid = tid >> 6, lane = tid & 63;
  int wr = (wid >> 1)*32, wc = (wid & 1)*32;
  int l15 = lane & 15, lk8 = (lane >> 4)*8;
  f32_4 a1c[2][2] = {}, a2c[2][2] = {};
  char* AsB = (char*)As;
  char* B1B = (char*)B1s;
  char* B2B = (char*)B2s;
  int wb = srow*128 + sseg*32;
  int swz = (srow & 7) << 4;
  {
    const u16* Ag = Abf + (size_t)(m0+srow)*KP + OFF_H + sseg*16;
    const u16* W1g = W1b + (size_t)(c0+srow)*HH + sseg*16;
    const u16* W2g = W2b + (size_t)(c0+srow)*HH + sseg*16;
    u16_8 a0 = *(const u16_8*)(Ag);
    u16_8 a1 = *(const u16_8*)(Ag + 8);
    u16_8 w10 = *(const u16_8*)(W1g);
    u16_8 w11 = *(const u16_8*)(W1g + 8);
    u16_8 w20 = *(const u16_8*)(W2g);
    u16_8 w21 = *(const u16_8*)(W2g + 8);
    *(u16_8*)(AsB + ((wb     ) ^ swz)) = a0;
    *(u16_8*)(AsB + ((wb + 16) ^ swz)) = a1;
    *(u16_8*)(B1B + ((wb     ) ^ swz)) = w10;
    *(u16_8*)(B1B + ((wb + 16) ^ swz)) = w11;
    *(u16_8*)(B2B + ((wb     ) ^ swz)) = w20;
    *(u16_8*)(B2B + ((wb + 16) ^ swz)) = w21;
  }
  __syncthreads();
  #pragma unroll
  for (int kk = 0; kk < 64; kk += 32) {
    bf16_8 av[2], b1v[2], b2v[2];
    #pragma unroll
    for (int mi = 0; mi < 2; ++mi) {
      int r = wr + mi*16 + l15;
      av[mi] = *(const bf16_8*)(AsB + ((r*128 + (kk+lk8)*2) ^ ((r&7)<<4)));
    }
    #pragma unroll
    for (int ni = 0; ni < 2; ++ni) {
      int cc = wc + ni*16 + l15;
      b1v[ni] = *(const bf16_8*)(B1B + ((cc*128 + (kk+lk8)*2) ^ ((cc&7)<<4)));
      b2v[ni] = *(const bf16_8*)(B2B + ((cc*128 + (kk+lk8)*2) ^ ((cc&7)<<4)));
    }
    #pragma unroll
    for (int mi = 0; mi < 2; ++mi)
      #pragma unroll
      for (int ni = 0; ni < 2; ++ni) {
        a1c[mi][ni] = __builtin_amdgcn_mfma_f32_16x16x32_bf16(av[mi], b1v[ni], a1c[mi][ni], 0, 0, 0);
        a2c[mi][ni] = __builtin_amdgcn_mfma_f32_16x16x32_bf16(av[mi], b2v[ni], a2c[mi][ni], 0, 0, 0);
      }
  }
  float s1 = 0.0f, sm = 0.0f;
  #pragma unroll
  for (int mi = 0; mi < 2; ++mi)
    #pragma unroll
    for (int ni = 0; ni < 2; ++ni) {
      int col = c0 + wc + ni*16 + l15;
      if (col < FF) {
        float hb = histb[col], eb = encb[col];
        #pragma unroll
        for (int r = 0; r < 4; ++r) {
          int row = m0 + wr + mi*16 + (lane>>4)*4 + r;
          size_t off = ((size_t)row*TT + t)*FF + col;
          float xh = a1c[mi][ni][r] + hb;
          float x = values[off], m = masks[off];
          float xc = m*x + (1.0f - m)*xh;
          out[OUT_IMP + off] = rnd6(xc);
          Abf[(size_t)row*KP + col] = bf16u(xc);
          Abf[(size_t)row*KP + OFF_M + col] = bf16u(m);
          float e = tanhf(a2c[mi][ni][r] + eb) * m;
          encout[((size_t)row*TT + t)*ELD + col] = bf16u(e);
          float d = x - xh;
          s1 += m*d*d;
          sm += m;
        }
      }
    }
  acc2_block(s1, sm, &acc[t], &acc[5+t]);
}

// ---------------- K3a: gates MFMA GEMM: [8192 x 1920] bf16 @ [256 x 1920]^T ----------------
__global__ __launch_bounds__(256) void k_gates_mfma(
    const u16* __restrict__ A, const u16* __restrict__ W,
    const float* __restrict__ bias, float* __restrict__ gates)
{
  __shared__ __align__(16) u16 As[64*64];
  __shared__ __align__(16) u16 Bs[64*64];
  int tid = threadIdx.x;
  int m0 = blockIdx.x*64, n0 = blockIdx.y*64;
  int srow = tid >> 2, sseg = tid & 3;
  int wid = tid >> 6, lane = tid & 63;
  int wr = (wid >> 1)*32, wc = (wid & 1)*32;
  int l15 = lane & 15, lk8 = (lane >> 4)*8;
  f32_4 acc[2][2] = {};
  const u16* Ag = A + (size_t)(m0+srow)*KP + sseg*16;
  const u16* Wg = W + (size_t)(n0+srow)*KP + sseg*16;
  char* AsB = (char*)As;
  char* BsB = (char*)Bs;
  int wb = srow*128 + sseg*32;
  int swz = (srow & 7) << 4;
  for (int k0 = 0; k0 < KP; k0 += 64) {
    u16_8 a0 = *(const u16_8*)(Ag + k0);
    u16_8 a1 = *(const u16_8*)(Ag + k0 + 8);
    u16_8 b0 = *(const u16_8*)(Wg + k0);
    u16_8 b1 = *(const u16_8*)(Wg + k0 + 8);
    *(u16_8*)(AsB + ((wb     ) ^ swz)) = a0;
    *(u16_8*)(AsB + ((wb + 16) ^ swz)) = a1;
    *(u16_8*)(BsB + ((wb     ) ^ swz)) = b0;
    *(u16_8*)(BsB + ((wb + 16) ^ swz)) = b1;
    __syncthreads();
    #pragma unroll
    for (int kk = 0; kk < 64; kk += 32) {
      bf16_8 av[2], bv[2];
      #pragma unroll
      for (int mi = 0; mi < 2; ++mi) {
        int r = wr + mi*16 + l15;
        av[mi] = *(const bf16_8*)(AsB + ((r*128 + (kk+lk8)*2) ^ ((r&7)<<4)));
      }
      #pragma unroll
      for (int ni = 0; ni < 2; ++ni) {
        int cc = wc + ni*16 + l15;
        bv[ni] = *(const bf16_8*)(BsB + ((cc*128 + (kk+lk8)*2) ^ ((cc&7)<<4)));
      }
      #pragma unroll
      for (int mi = 0; mi < 2; ++mi)
        #pragma unroll
        for (int ni = 0; ni < 2; ++ni)
          acc[mi][ni] = __builtin_amdgcn_mfma_f32_16x16x32_bf16(av[mi], bv[ni], acc[mi][ni], 0, 0, 0);
    }
    __syncthreads();
  }
  #pragma unroll
  for (int mi = 0; mi < 2; ++mi)
    #pragma unroll
    for (int ni = 0; ni < 2; ++ni) {
      int col = n0 + wc + ni*16 + l15;
      float bb = bias[col];
      #pragma unroll
      for (int r = 0; r < 4; ++r) {
        int row = m0 + wr + mi*16 + (lane>>4)*4 + r;
        gates[(size_t)row*NG + col] = acc[mi][ni][r] + bb;
      }
    }
}

// ---------------- K4: proj MFMA GEMM -> bf16 outputs ----------------
__global__ __launch_bounds__(256) void k_proj_mfma(
    const u16* __restrict__ A, const u16* __restrict__ W,
    const float* __restrict__ attb,
    u16* __restrict__ encWpB, u16* __restrict__ encAB)
{
  __shared__ __align__(16) u16 As[64*64];
  __shared__ __align__(16) u16 Bs[64*64];
  int tid = threadIdx.x;
  int m0 = blockIdx.x*64, n0 = blockIdx.y*64;
  int srow = tid >> 2, sseg = tid & 3;
  int wid = tid >> 6, lane = tid & 63;
  int wr = (wid >> 1)*32, wc = (wid & 1)*32;
  int l15 = lane & 15, lk8 = (lane >> 4)*8;
  f32_4 acc[2][2] = {};
  const u16* Ag = A + (size_t)(m0+srow)*ELD + sseg*16;
  const u16* Wg = W + (size_t)(n0+srow)*PKP + sseg*16;
  char* AsB = (char*)As;
  char* BsB = (char*)Bs;
  int wb = srow*128 + sseg*32;
  int swz = (srow & 7) << 4;
  for (int k0 = 0; k0 < PKP; k0 += 64) {
    u16_8 a0, a1;
    if (k0 < ELD) {
      a0 = *(const u16_8*)(Ag + k0);
      a1 = *(const u16_8*)(Ag + k0 + 8);
    } else {
      a0 = (u16_8)0; a1 = (u16_8)0;
    }
    u16_8 b0 = *(const u16_8*)(Wg + k0);
    u16_8 b1 = *(const u16_8*)(Wg + k0 + 8);
    *(u16_8*)(AsB + ((wb     ) ^ swz)) = a0;
    *(u16_8*)(AsB + ((wb + 16) ^ swz)) = a1;
    *(u16_8*)(BsB + ((wb     ) ^ swz)) = b0;
    *(u16_8*)(BsB + ((wb + 16) ^ swz)) = b1;
    __syncthreads();
    #pragma unroll
    for (int kk = 0; kk < 64; kk += 32) {
      bf16_8 av[2], bv[2];
      #pragma unroll
      for (int mi = 0; mi < 2; ++mi) {
        int r = wr + mi*16 + l15;
        av[mi] = *(const bf16_8*)(AsB + ((r*128 + (kk+lk8)*2) ^ ((r&7)<<4)));
      }
      #pragma unroll
      for (int ni = 0; ni < 2; ++ni) {
        int cc = wc + ni*16 + l15;
        bv[ni] = *(const bf16_8*)(BsB + ((cc*128 + (kk+lk8)*2) ^ ((cc&7)<<4)));
      }
      #pragma unroll
      for (int mi = 0; mi < 2; ++mi)
        #pragma unroll
        for (int ni = 0; ni < 2; ++ni)
          acc[mi][ni] = __builtin_amdgcn_mfma_f32_16x16x32_bf16(av[mi], bv[ni], acc[mi][ni], 0, 0, 0);
    }
    __syncthreads();
  }
  #pragma unroll
  for (int mi = 0; mi < 2; ++mi)
    #pragma unroll
    for (int ni = 0; ni < 2; ++ni) {
      int col = n0 + wc + ni*16 + l15;
      if (col < NG) {
        #pragma unroll
        for (int r = 0; r < 4; ++r) {
          int row = m0 + wr + mi*16 + (lane>>4)*4 + r;
          encWpB[(size_t)row*NG + col] = bf16u(acc[mi][ni][r]);
        }
      } else {
        float bb = attb[col - NG];
        #pragma unroll
        for (int r = 0; r < 4; ++r) {
          int row = m0 + wr + mi*16 + (lane>>4)*4 + r;
          encAB[(size_t)row*HH + (col - NG)] = bf16u(acc[mi][ni][r] + bb);
        }
      }
    }
}

// ---------------- K3b: LSTM pointwise + fused next-step gamma + bf16 h ----------------
__global__ __launch_bounds__(256) void k_lstm(
    const float* __restrict__ gates, float* __restrict__ h, float* __restrict__ c,
    const float* __restrict__ G, u16* __restrict__ Abf, u16* __restrict__ hb16, int t)
{
  int idx = blockIdx.x*256 + threadIdx.x;
  int b = idx >> 6, u = idx & 63;
  const float* g = gates + (size_t)b*NG;
  float gi = g[u], gf = g[64+u], gg = g[128+u], go = g[192+u];
  float cn = sigm(gf)*c[idx] + sigm(gi)*tanhf(gg);
  float hn = sigm(go)*tanhf(cn);
  c[idx] = cn;
  float hs = hn;
  if (t < TT-1) hs *= G[((size_t)b*TT + t + 1)*HH + u];
  h[idx] = hs;
  Abf[(size_t)b*KP + OFF_H + u] = bf16u(hs);
  if (t == TT-1) hb16[idx] = bf16u(hn);
}

// ---------------- K5: y_h init (wave per row), decoded[:,T-1], y_loss td=0 ----------------
__global__ __launch_bounds__(256) void k_yh0(
    const float* __restrict__ h, const float* __restrict__ outW,
    const float* __restrict__ outb, const float* __restrict__ labels,
    const float* __restrict__ masksy, float* __restrict__ out,
    float* __restrict__ yh, double* __restrict__ acc)
{
  int tid = threadIdx.x;
  int wid = tid >> 6, lane = tid & 63;
  int b = blockIdx.x*4 + wid;
  float hv = h[(size_t)b*HH + lane];
  float p0 = hv*outW[lane], p1 = hv*outW[HH+lane];
  #pragma unroll
  for (int off = 32; off > 0; off >>= 1) {
    p0 += __shfl_xor(p0, off, 64);
    p1 += __shfl_xor(p1, off, 64);
  }
  float y0 = p0 + outb[0], y1 = p1 + outb[1];
  size_t lo = ((size_t)b*TT + (TT-1))*2;
  float l0 = labels[lo], l1 = labels[lo+1];
  float m0 = masksy[lo], m1 = masksy[lo+1];
  if (lane == 0) {
    out[OUT_DEC + lo]   = rnd6(l0*m0 + y0*(1.0f-m0));
    out[OUT_DEC + lo+1] = rnd6(l1*m1 + y1*(1.0f-m1));
    yh[b*2]   = y0;
    yh[b*2+1] = y1;
  }
  float d0 = (y0-l0)*m0, d1 = (y1-l1)*m1;
  float sl  = (lane==0) ? (d0*d0 + d1*d1) : 0.0f;
  float smk = (lane==0) ? (m0+m1) : 0.0f;
  acc2_block(sl, smk, &acc[10], &acc[15]);
}

// ---------------- K6a: decoder GEMM: P[8192x320] = hb16 @ [attW64 ; decWhh]^T ----------------
__global__ __launch_bounds__(64) void k_dec_gemm(
    const u16* __restrict__ hb16, const u16* __restrict__ dwcat,
    float* __restrict__ P)
{
  int lane = threadIdx.x & 63;
  int row0 = blockIdx.x*16;
  int l15 = lane & 15, lk8 = (lane >> 4)*8;
  const u16* Ab = hb16 + (size_t)(row0 + l15)*HH;
  bf16_8 av0 = *(const bf16_8*)(Ab + lk8);
  bf16_8 av1 = *(const bf16_8*)(Ab + 32 + lk8);
  f32_4 acc[20];
  #pragma unroll
  for (int nb = 0; nb < 20; ++nb) {
    const u16* Bb = dwcat + (size_t)(nb*16 + l15)*HH;
    bf16_8 bv0 = *(const bf16_8*)(Bb + lk8);
    bf16_8 bv1 = *(const bf16_8*)(Bb + 32 + lk8);
    f32_4 a = {};
    a = __builtin_amdgcn_mfma_f32_16x16x32_bf16(av0, bv0, a, 0, 0, 0);
    a = __builtin_amdgcn_mfma_f32_16x16x32_bf16(av1, bv1, a, 0, 0, 0);
    acc[nb] = a;
  }
  #pragma unroll
  for (int nb = 0; nb < 20; ++nb) {
    #pragma unroll
    for (int r = 0; r < 4; ++r) {
      int row = row0 + (lane>>4)*4 + r;
      P[(size_t)row*DN + nb*16 + l15] = acc[nb][r];
    }
  }
}

// ---------------- K6b: decoder pointwise (wave per row) ----------------
__global__ __launch_bounds__(256) void k_dec_pw(
    const float* __restrict__ labels, const float* __restrict__ masksy,
    const float* __restrict__ dw01, const float* __restrict__ decb,
    const float* __restrict__ attv, const float* __restrict__ outW,
    const float* __restrict__ outb, float* __restrict__ c,
    float* __restrict__ yh, const u16* __restrict__ encWpB,
    const u16* __restrict__ encAB, const float* __restrict__ P,
    u16* __restrict__ hb16, float* __restrict__ out,
    double* __restrict__ acc, int td)
{
  int tid = threadIdx.x;
  int wid = tid >> 6, lane = tid & 63;
  int b = blockIdx.x*4 + wid;
  int u = lane;
  float hA = P[(size_t)b*DN + u];
  float cj = c[(size_t)b*HH + u];
  float vj = attv[u];
  float sc[5];
  #pragma unroll
  for (int s = 0; s < 5; ++s) {
    float e = tanhf(hA + ubf(encAB[((size_t)b*TT + s)*HH + u]));
    float p = e*vj;
    #pragma unroll
    for (int off = 32; off > 0; off >>= 1) p += __shfl_xor(p, off, 64);
    sc[s] = p;
  }
  float mx = fmaxf(fmaxf(fmaxf(sc[0],sc[1]),fmaxf(sc[2],sc[3])),sc[4]);
  float se = 0.0f;
  #pragma unroll
  for (int s = 0; s < 5; ++s) { sc[s] = expf(sc[s]-mx); se += sc[s]; }
  float inv = 1.0f/se;
  #pragma unroll
  for (int s = 0; s < 5; ++s) sc[s] *= inv;
  int tt = TT-1-td;
  size_t lo = ((size_t)b*TT + tt)*2;
  float l0 = labels[lo], l1 = labels[lo+1];
  float m0 = masksy[lo], m1 = masksy[lo+1];
  float py0 = yh[b*2], py1 = yh[b*2+1];
  float iy0 = fmaf(l0, m0, py0*(1.0f-m0));
  float iy1 = fmaf(l1, m1, py1*(1.0f-m1));
  if (lane < 2) out[OUT_DEC + lo + lane] = rnd6(lane ? iy1 : iy0);
  float g[4];
  #pragma unroll
  for (int gi = 0; gi < 4; ++gi) {
    int jj = gi*64 + u;
    float a = decb[jj] + iy0*dw01[2*jj] + iy1*dw01[2*jj+1] + P[(size_t)b*DN + 64 + jj];
    #pragma unroll
    for (int s = 0; s < 5; ++s)
      a = fmaf(sc[s], ubf(encWpB[((size_t)b*TT + s)*NG + jj]), a);
    g[gi] = a;
  }
  float cn = sigm(g[1])*cj + sigm(g[0])*tanhf(g[2]);
  float hn = sigm(g[3])*tanhf(cn);
  c[(size_t)b*HH + u] = cn;
  hb16[(size_t)b*HH + u] = bf16u(hn);
  float p0 = hn*outW[u], p1 = hn*outW[HH+u];
  #pragma unroll
  for (int off = 32; off > 0; off >>= 1) {
    p0 += __shfl_xor(p0, off, 64);
    p1 += __shfl_xor(p1, off, 64);
  }
  float ny0 = p0 + outb[0], ny1 = p1 + outb[1];
  if (lane == 0) { yh[b*2] = ny0; yh[b*2+1] = ny1; }
  float d0 = (ny0-l0)*m0, d1 = (ny1-l1)*m1;
  float sl  = (lane==0) ? (d0*d0 + d1*d1) : 0.0f;
  float smk = (lane==0) ? (m0+m1) : 0.0f;
  acc2_block(sl, smk, &acc[10+td], &acc[15+td]);
}

// ---------------- K7: finalize loss ----------------
__global__ void k_loss(const double* __restrict__ acc, float* __restrict__ out)
{
  if (threadIdx.x == 0 && blockIdx.x == 0) {
    double xl = 0.0, yl = 0.0;
    for (int t = 0; t < 5; ++t)
      xl += acc[t] / ((double)BB*FF) / (acc[5+t] + 1e-5);
    for (int d = 0; d < 5; ++d)
      yl += acc[10+d] / ((double)BB*2) / (acc[15+d] + 1e-5);
    out[0] = (float)((xl + yl) / 5.0);
  }
}

extern "C" void kernel_launch(void* const* d_in, const int* in_sizes, int n_in,
                              void* d_out, int out_size, void* d_ws, size_t ws_size,
                              hipStream_t stream)
{
  const float* values = (const float*)d_in[0];
  const float* masks  = (const float*)d_in[1];
  const float* deltas = (const float*)d_in[2];
  const float* labels = (const float*)d_in[3];
  const float* masksy = (const float*)d_in[4];
  const float* tdW    = (const float*)d_in[5];
  const float* tdb    = (const float*)d_in[6];
  const float* histW  = (const float*)d_in[7];
  const float* histb  = (const float*)d_in[8];
  const float* encWt  = (const float*)d_in[9];
  const float* encb   = (const float*)d_in[10];
  const float* rnnWih = (const float*)d_in[11];
  const float* rnnWhh = (const float*)d_in[12];
  const float* rnnb   = (const float*)d_in[13];
  const float* decWih = (const float*)d_in[14];
  const float* decWhh = (const float*)d_in[15];
  const float* decb   = (const float*)d_in[16];
  const float* attW   = (const float*)d_in[17];
  const float* attb   = (const float*)d_in[18];
  const float* attv   = (const float*)d_in[19];
  const float* outW   = (const float*)d_in[20];
  const float* outb   = (const float*)d_in[21];
  float* out = (float*)d_out;
  char* ws = (char*)d_ws;
  double* acc = (double*)ws;
  float* h      = (float*)(ws + H_OFF);
  float* c      = (float*)(ws + C_OFF);
  float* yh     = (float*)(ws + YH_OFF);
  float* gates  = (float*)(ws + GATES_OFF);
  float* G      = (float*)(ws + G_OFF);
  u16*   Abf    = (u16*)(ws + ABF_OFF);
  u16*   tdWb   = (u16*)(ws + TDWB_OFF);
  u16*   W1b    = (u16*)(ws + W1B_OFF);
  u16*   W2b    = (u16*)(ws + W2B_OFF);
  u16*   dwcat  = (u16*)(ws + DWCAT_OFF);
  float* dw01   = (float*)(ws + DW01_OFF);
  u16*   hb16   = (u16*)(ws + HB16_OFF);
  u16*   encWpB = (u16*)(ws + ENCW_OFF);
  u16*   encAB  = (u16*)(ws + ENCA_OFF);
  u16*   rnnWb  = (u16*)(ws + RWB_OFF);
  u16*   projWb = (u16*)(ws + PWB_OFF);
  u16*   encout = (u16*)(ws + ENCOUT_OFF);
  float* P      = (float*)(ws + P_OFF);

  (void)hipMemsetAsync(d_ws, 0, ZERO_BYTES, stream);

  k_prep<<<5970, 256, 0, stream>>>(rnnWih, rnnWhh, decWih, attW, tdW, histW, encWt,
                                   decWhh, rnnWb, projWb, Abf, tdWb, W1b, W2b, dwcat, dw01);
  k_gamma_mfma<<<640, 256, 0, stream>>>(deltas, tdWb, tdb, G);

  for (int t = 0; t < TT; ++t) {
    k_xh_enc_mfma<<<dim3(BB/64, 15), 256, 0, stream>>>(values, masks, W1b, W2b,
                                                       histb, encb, out, Abf, encout, acc, t);
    k_gates_mfma<<<dim3(BB/64, 4), 256, 0, stream>>>(Abf, rnnWb, rnnb, gates);
    k_lstm<<<BB*HH/256, 256, 0, stream>>>(gates, h, c, G, Abf, hb16, t);
  }
  k_proj_mfma<<<dim3(BB*TT/64, 5), 256, 0, stream>>>(encout, projWb, attb, encWpB, encAB);
  k_yh0<<<BB/4, 256, 0, stream>>>(h, outW, outb, labels, masksy, out, yh, acc);
  for (int td = 1; td < TT; ++td) {
    k_dec_gemm<<<BB/16, 64, 0, stream>>>(hb16, dwcat, P);
    k_dec_pw<<<BB/4, 256, 0, stream>>>(labels, masksy, dw01, decb, attv, outW, outb,
                                       c, yh, encWpB, encAB, P, hb16, out, acc, td);
  }
  k_loss<<<1, 1, 0, stream>>>(acc, out);
}